// Round 10
// baseline (441.106 us; speedup 1.0000x reference)
//
#include <hip/hip_runtime.h>
#include <math.h>

#define H 512
#define GV 640
#define E_DIM 256
#define BM 64
#define KSTEP 32
#define NKT (H / KSTEP)   // 16

typedef _Float16 half8 __attribute__((ext_vector_type(8)));
typedef float f32x4 __attribute__((ext_vector_type(4)));

// ---- ws layout (interleaved hi/lo images: granule = 32 B = {half8 hi, half8 lo}) ----
#define WS_WI   4096                                   // W image: 40960 granules
#define WS_XI   (WS_WI + 40960 * 32)                   // X image: (B*64) granules
#define WS_CVAL(B) (WS_XI + (size_t)(B) * 64 * 32)
#define WS_CIDX(B) (WS_CVAL(B) + (size_t)(B) * 10 * 4)
#define WS_NEED_FULL(B) (WS_CIDX(B) + (size_t)(B) * 10 * 4)
#define WS_NEED_MID  (WS_WI + 40960 * 32)

__device__ __forceinline__ f32x4 MF(half8 a, half8 b, f32x4 c) {
    return __builtin_amdgcn_mfma_f32_16x16x32_f16(a, b, c, 0, 0, 0);
}

// ---------------- prep W: (640x512 f32) -> interleaved fp16 hi/lo, fragment-order ----------------
__global__ void prep_w(const float* __restrict__ W, _Float16* __restrict__ wi)
{
    int t = blockIdx.x * 256 + threadIdx.x;      // 0..40959
    int kt = t / 2560;
    int rem = t % 2560;
    int g = rem / 640;
    int col = rem - g * 640;
    int k = kt * KSTEP + g * 8;
    const float* src = W + (size_t)col * H + k;
    float4 v0 = *(const float4*)src;
    float4 v1 = *(const float4*)(src + 4);
    float vv[8] = {v0.x, v0.y, v0.z, v0.w, v1.x, v1.y, v1.z, v1.w};
    half8 hv, lv;
    #pragma unroll
    for (int i = 0; i < 8; ++i) {
        float ws_ = vv[i] * 1024.0f;
        _Float16 h = (_Float16)ws_;
        hv[i] = h;
        lv[i] = (_Float16)(ws_ - (float)h);
    }
    ((half8*)wi)[2 * t]     = hv;
    ((half8*)wi)[2 * t + 1] = lv;
}

// ---------------- prep X: (B x 512 f32) -> interleaved fp16 hi/lo, row-major granules ----------
__global__ void prep_x(const float* __restrict__ hid, _Float16* __restrict__ xi)
{
    int t = blockIdx.x * 256 + threadIdx.x;
    int row = t >> 6, c = t & 63;
    const float* src = hid + (size_t)row * H + c * 8;
    float4 v0 = *(const float4*)src;
    float4 v1 = *(const float4*)(src + 4);
    float vv[8] = {v0.x, v0.y, v0.z, v0.w, v1.x, v1.y, v1.z, v1.w};
    half8 hv, lv;
    #pragma unroll
    for (int i = 0; i < 8; ++i) {
        float xs = vv[i] * 64.0f;
        _Float16 h = (_Float16)xs;
        hv[i] = h;
        lv[i] = (_Float16)(xs - (float)h);
    }
    ((half8*)xi)[2 * t]     = hv;
    ((half8*)xi)[2 * t + 1] = lv;
}

// ---------------- main GEMM: barrier-free, zero LDS, register-pipelined ----------------
// Grid (B/64)*5, XCD-chunked. Block 256 thr = 4 waves (wr,wc): 64 rows x 128 cols.
// Wave = 32 rows x 64 cols; acc[2][4] = 32 regs. K-loop software-pipelined in registers:
// A prefetched one kt ahead, B rotated at half-kt granularity -> every load batch issued
// >=12 MFMAs before first use; compiler's counted vmcnt keeps loads in flight.
// Reg budget: 32 acc + 64 frag + ~15 addr ~= 110 < 128 (4 waves/SIMD).
template<int NT0>
__device__ __forceinline__ void mm2(f32x4 (&acc)[2][4], const half8* AH, const half8* AL,
                                    const half8* BH, const half8* BL)
{
    #pragma unroll
    for (int j = 0; j < 2; ++j)
        #pragma unroll
        for (int mt = 0; mt < 2; ++mt) {
            acc[mt][NT0 + j] = MF(AH[mt], BH[j], acc[mt][NT0 + j]);
            acc[mt][NT0 + j] = MF(AH[mt], BL[j], acc[mt][NT0 + j]);
            acc[mt][NT0 + j] = MF(AL[mt], BH[j], acc[mt][NT0 + j]);
        }
}

__global__ __launch_bounds__(256, 4) void gemm32i(
    const float* __restrict__ noise,   // (B,640)
    const float* __restrict__ bias,    // (640)
    const _Float16* __restrict__ wi,   // interleaved W image
    const _Float16* __restrict__ xi,   // interleaved X image
    float* __restrict__ cval,          // (B,10)
    int* __restrict__ cidx)            // (B,10)
{
    int bid = blockIdx.x, nb = gridDim.x;
    const int lb = ((nb & 7) == 0) ? ((bid & 7) * (nb >> 3) + (bid >> 3)) : bid;
    const int rowslice = lb / 5;
    const int cb2 = lb - rowslice * 5;           // 128-col block 0..4
    const int brow = rowslice * BM;

    const int tid = threadIdx.x;
    const int wid = tid >> 6;
    const int wr = wid >> 1, wc = wid & 1;
    const int l = tid & 63;
    const int q = l & 15, g = l >> 4;
    const int colw = cb2 * 128 + wc * 64;        // wave's col base

    f32x4 acc[2][4];
    #pragma unroll
    for (int mt = 0; mt < 2; ++mt)
        #pragma unroll
        for (int nt = 0; nt < 4; ++nt)
            acc[mt][nt] = (f32x4){0.f, 0.f, 0.f, 0.f};

    const half8* xv = (const half8*)xi;
    const half8* wv = (const half8*)wi;
    const size_t arow0 = (size_t)(brow + wr * 32 + q);       // A rows: arow0, arow0+16

// A granules for (kt, mt): index 2*((arow0+mt*16)*64 + kt*4 + g)
#define LA(AH, AL, KT) { \
    size_t i0 = 2 * (arow0 * 64 + (size_t)((KT) * 4 + g)); \
    AH[0] = xv[i0];            AL[0] = xv[i0 + 1]; \
    AH[1] = xv[i0 + 2048];     AL[1] = xv[i0 + 2049]; }
// B granules for (kt, nt0..nt0+1): index 2*(((kt*4+g)*640) + colw + q + nt*16)
#define LB(BH, BL, KT, NT0) { \
    size_t ib = 2 * ((size_t)(((KT) * 4 + g) * 640) + colw + q + (NT0) * 16); \
    BH[0] = wv[ib];        BL[0] = wv[ib + 1]; \
    BH[1] = wv[ib + 32];   BL[1] = wv[ib + 33]; }

    half8 A0h[2], A0l[2], A1h[2], A1l[2];
    half8 Bah[2], Bal[2], Bbh[2], Bbl[2];

    LA(A0h, A0l, 0);
    LB(Bah, Bal, 0, 0);
    #pragma unroll
    for (int kt = 0; kt < NKT; kt += 2) {
        LB(Bbh, Bbl, kt, 2);                       // current kt, nt23
        LA(A1h, A1l, kt + 1);                      // next kt's A
        mm2<0>(acc, A0h, A0l, Bah, Bal);           // consume kt nt01
        LB(Bah, Bal, kt + 1, 0);                   // next kt nt01
        mm2<2>(acc, A0h, A0l, Bbh, Bbl);           // consume kt nt23
        LB(Bbh, Bbl, kt + 1, 2);                   // next kt nt23
        if (kt + 2 < NKT) LA(A0h, A0l, kt + 2);    // kt+2's A
        mm2<0>(acc, A1h, A1l, Bah, Bal);           // consume kt+1 nt01
        if (kt + 2 < NKT) LB(Bah, Bal, kt + 2, 0); // kt+2 nt01
        mm2<2>(acc, A1h, A1l, Bbh, Bbl);           // consume kt+1 nt23
    }
#undef LA
#undef LB

    // ---- epilogue: z = logits + bias + gumbel; per-row argmax over this wave's 64 cols ----
    const float C1 = 1.52587890625e-05f;        // 2^-16 (64*1024 product scale)
    float bcol[4];
    #pragma unroll
    for (int nt = 0; nt < 4; ++nt) bcol[nt] = bias[colw + nt * 16 + q];

    const int cb10 = cb2 * 2 + wc;               // 64-col candidate slot 0..9
    #pragma unroll
    for (int mt = 0; mt < 2; ++mt) {
        #pragma unroll
        for (int reg = 0; reg < 4; ++reg) {
            const int rloc = wr * 32 + mt * 16 + g * 4 + reg;
            float bv = -INFINITY;
            int bn = 0;
            #pragma unroll
            for (int nt = 0; nt < 4; ++nt) {
                int col = colw + nt * 16 + q;
                float u = noise[(size_t)(brow + rloc) * GV + col];
                float gum = -logf(-logf(u + 1e-10f) + 1e-10f);
                float z = acc[mt][nt][reg] * C1 + bcol[nt] + gum;
                if (z > bv) { bv = z; bn = col; }            // ascending: first-wins
            }
            #pragma unroll
            for (int m = 1; m < 16; m <<= 1) {               // 16-lane argmax reduce
                float ov = __shfl_xor(bv, m, 64);
                int on = __shfl_xor(bn, m, 64);
                if (ov > bv || (ov == bv && on < bn)) { bv = ov; bn = on; }
            }
            if (q == 0) {
                cval[(size_t)(brow + rloc) * 10 + cb10] = bv;
                cidx[(size_t)(brow + rloc) * 10 + cb10] = bn;
            }
        }
    }
}

// ---------------- reduce: final argmax per (row,group), histogram, gather ----------------
__global__ __launch_bounds__(256) void reduce_gather(
    const float* __restrict__ cval, const int* __restrict__ cidx,
    const float* __restrict__ emb, float* __restrict__ out, int* __restrict__ cnt)
{
    const int tid = threadIdx.x;
    const int task = blockIdx.x * 4 + (tid >> 6);
    const int lane = tid & 63;
    const int row = task >> 1, grp = task & 1;

    float bv = -INFINITY;
    int bn = 0;
    #pragma unroll
    for (int cb = 0; cb < 5; ++cb) {
        float v = cval[(size_t)row * 10 + grp * 5 + cb];
        int n = cidx[(size_t)row * 10 + grp * 5 + cb];
        if (v > bv) { bv = v; bn = n; }                      // ascending colblk
    }
    if (lane == 0) atomicAdd(&cnt[bn], 1);
    const float4* src = (const float4*)(emb + (size_t)bn * E_DIM);
    float4* dst = (float4*)(out + (size_t)row * 512 + grp * 256);
    dst[lane] = src[lane];
}

__global__ void ppl_kernel(const int* __restrict__ cnt, float* __restrict__ outp)
{
    const int lane = threadIdx.x;
    float total = 0.f;
    #pragma unroll
    for (int gg = 0; gg < 2; ++gg) {
        float s = 0.f;
        for (int v = lane; v < 320; v += 64) {
            float m = (float)cnt[gg * 320 + v] * (1.0f / 65536.0f);
            s += m * logf(m + 1e-7f);
        }
        #pragma unroll
        for (int msk = 1; msk <= 32; msk <<= 1) s += __shfl_xor(s, msk, 64);
        total += expf(-s);
    }
    if (lane == 0) *outp = total;
}

// ---------------- mid fallback: LDS-staged kernel (interleaved W image) ------
__global__ __launch_bounds__(640) void gemm_argmax_mid(
    const float* __restrict__ hid, const float* __restrict__ noise,
    const float* __restrict__ emb, const float* __restrict__ bias,
    const _Float16* __restrict__ wi,
    float* __restrict__ out, int* __restrict__ cnt)
{
    __shared__ __align__(16) _Float16 Xh[BM][KSTEP];
    __shared__ __align__(16) _Float16 Xl[BM][KSTEP];
    __shared__ int sel_n[BM][2];
    float* red_val = (float*)&Xh[0][0];
    int*   red_idx = (int*)&Xl[0][0];

    const int tid = threadIdx.x;
    const int w = tid >> 6;
    const int l = tid & 63;
    const int q = l & 15, g = l >> 4;
    const int sig = (q >> 1) & 3;
    const int sl = (g ^ sig) * 8;
    const int brow = blockIdx.x * BM;

    f32x4 acc[4][4];
    #pragma unroll
    for (int mt = 0; mt < 4; ++mt)
        #pragma unroll
        for (int nt = 0; nt < 4; ++nt) acc[mt][nt] = (f32x4){0.f, 0.f, 0.f, 0.f};

    const half8* wv = (const half8*)wi;

    for (int kt = 0; kt < NKT; ++kt) {
        __syncthreads();
        if (tid < 256) {
            int r = tid & 63, c = tid >> 6;
            const float* src = hid + (size_t)(brow + r) * H + kt * KSTEP + c * 8;
            float4 v0 = *(const float4*)src;
            float4 v1 = *(const float4*)(src + 4);
            float vv[8] = {v0.x, v0.y, v0.z, v0.w, v1.x, v1.y, v1.z, v1.w};
            half8 hv, lv;
            #pragma unroll
            for (int i = 0; i < 8; ++i) {
                float xs = vv[i] * 64.0f;
                _Float16 h = (_Float16)xs;
                hv[i] = h;
                lv[i] = (_Float16)(xs - (float)h);
            }
            int slot = c ^ ((r >> 1) & 3);
            *(half8*)&Xh[r][slot * 8] = hv;
            *(half8*)&Xl[r][slot * 8] = lv;
        }
        __syncthreads();
        half8 Ah[4], Al[4];
        #pragma unroll
        for (int mt = 0; mt < 4; ++mt) {
            int row = mt * 16 + q;
            Ah[mt] = *(const half8*)&Xh[row][sl];
            Al[mt] = *(const half8*)&Xl[row][sl];
        }
        const int gbase = (kt * 4 + g) * 640 + w * 64 + q;
        #pragma unroll
        for (int nt = 0; nt < 4; ++nt) {
            half8 Bh = wv[2 * (gbase + nt * 16)];
            half8 Bl = wv[2 * (gbase + nt * 16) + 1];
            #pragma unroll
            for (int mt = 0; mt < 4; ++mt) {
                acc[mt][nt] = MF(Ah[mt], Bh, acc[mt][nt]);
                acc[mt][nt] = MF(Ah[mt], Bl, acc[mt][nt]);
                acc[mt][nt] = MF(Al[mt], Bh, acc[mt][nt]);
            }
        }
    }
    __syncthreads();

    const float C1 = 1.52587890625e-05f;
    float bcol[4];
    #pragma unroll
    for (int nt = 0; nt < 4; ++nt) bcol[nt] = bias[w * 64 + nt * 16 + q];
    #pragma unroll
    for (int mt = 0; mt < 4; ++mt) {
        #pragma unroll
        for (int reg = 0; reg < 4; ++reg) {
            int r = mt * 16 + 4 * g + reg;
            float bv = -INFINITY;
            int bn = 0;
            #pragma unroll
            for (int nt = 0; nt < 4; ++nt) {
                int col = w * 64 + nt * 16 + q;
                float u = noise[(size_t)(brow + r) * GV + col];
                float gum = -logf(-logf(u + 1e-10f) + 1e-10f);
                float z = acc[mt][nt][reg] * C1 + bcol[nt] + gum;
                if (z > bv) { bv = z; bn = col; }
            }
            #pragma unroll
            for (int m = 1; m < 16; m <<= 1) {
                float ov = __shfl_xor(bv, m, 64);
                int on = __shfl_xor(bn, m, 64);
                if (ov > bv || (ov == bv && on < bn)) { bv = ov; bn = on; }
            }
            if (q == 0) { red_val[r * 10 + w] = bv; red_idx[r * 10 + w] = bn; }
        }
    }
    __syncthreads();
    if (tid < 128) {
        int r = tid >> 1, grp = tid & 1;
        float bv = -INFINITY;
        int bn = 0;
        #pragma unroll
        for (int ww = 0; ww < 5; ++ww) {
            int wiq = grp * 5 + ww;
            float v = red_val[r * 10 + wiq];
            int n = red_idx[r * 10 + wiq];
            if (v > bv) { bv = v; bn = n; }
        }
        atomicAdd(&cnt[bn], 1);
        sel_n[r][grp] = bn;
    }
    __syncthreads();
    if (tid < 512) {
        int rg = tid >> 2, sub = tid & 3;
        int r = rg >> 1, grp = rg & 1;
        int n = sel_n[r][grp];
        const float4* src = (const float4*)(emb + (size_t)n * E_DIM);
        float4* dst = (float4*)(out + (size_t)(brow + r) * 512 + grp * 256);
        #pragma unroll
        for (int j = 0; j < 16; ++j) dst[sub + j * 4] = src[sub + j * 4];
    }
}

// ---------------- last-resort fp32 fallback (round-1) ----------------
__global__ __launch_bounds__(512) void fused_gemm_argmax(
    const float* __restrict__ hid, const float* __restrict__ noise,
    const float* __restrict__ emb, const float* __restrict__ W,
    const float* __restrict__ bias, float* __restrict__ out, int* __restrict__ cnt)
{
    __shared__ float A_lds[16][64];
    __shared__ float B_lds[16][GV + 4];
    const int tid = threadIdx.x;
    const int tx = tid & 63, ty = tid >> 6;
    const int brow = blockIdx.x * 64;
    const int nbase = tx * 10;
    float acc[8][10];
    #pragma unroll
    for (int i = 0; i < 8; ++i)
        #pragma unroll
        for (int j = 0; j < 10; ++j) acc[i][j] = 0.f;
    for (int t = 0; t < H; t += 16) {
        if (t) __syncthreads();
        if (tid < 256) {
            int m = tid & 63, kq = tid >> 6;
            float4 v = *(const float4*)(hid + (size_t)(brow + m) * H + t + kq * 4);
            A_lds[kq * 4 + 0][m] = v.x; A_lds[kq * 4 + 1][m] = v.y;
            A_lds[kq * 4 + 2][m] = v.z; A_lds[kq * 4 + 3][m] = v.w;
        }
        #pragma unroll
        for (int s = 0; s < 5; ++s) {
            int c = tid + s * 512;
            int n = c % 640, kq = c / 640;
            float4 v = *(const float4*)(W + (size_t)n * H + t + kq * 4);
            B_lds[kq * 4 + 0][n] = v.x; B_lds[kq * 4 + 1][n] = v.y;
            B_lds[kq * 4 + 2][n] = v.z; B_lds[kq * 4 + 3][n] = v.w;
        }
        __syncthreads();
        #pragma unroll 4
        for (int kk = 0; kk < 16; ++kk) {
            float a[8], bb[10];
            #pragma unroll
            for (int i = 0; i < 8; ++i) a[i] = A_lds[kk][ty * 8 + i];
            #pragma unroll
            for (int j = 0; j < 10; ++j) bb[j] = B_lds[kk][nbase + j];
            #pragma unroll
            for (int i = 0; i < 8; ++i)
                #pragma unroll
                for (int j = 0; j < 10; ++j) acc[i][j] = fmaf(a[i], bb[j], acc[i][j]);
        }
    }
    float bs[10];
    #pragma unroll
    for (int j = 0; j < 10; ++j) bs[j] = bias[nbase + j];
    const int gg = tx >> 5, ll = tx & 31;
    #pragma unroll
    for (int i = 0; i < 8; ++i) {
        const int b = brow + ty * 8 + i;
        float best = -INFINITY; int bestn = nbase;
        #pragma unroll
        for (int j = 0; j < 10; ++j) {
            float u = noise[(size_t)b * GV + nbase + j];
            float gmb = -logf(-logf(u + 1e-10f) + 1e-10f);
            float z = acc[i][j] + bs[j] + gmb;
            if (z > best) { best = z; bestn = nbase + j; }
        }
        #pragma unroll
        for (int msk = 1; msk <= 16; msk <<= 1) {
            float oz = __shfl_xor(best, msk, 64);
            int on = __shfl_xor(bestn, msk, 64);
            if (oz > best || (oz == best && on < bestn)) { best = oz; bestn = on; }
        }
        if (ll == 0) atomicAdd(&cnt[bestn], 1);
        const float4* src = (const float4*)(emb + (size_t)bestn * E_DIM);
        float4* dst = (float4*)(out + (size_t)b * 512 + gg * 256);
        dst[ll] = src[ll];
        dst[ll + 32] = src[ll + 32];
    }
}

extern "C" void kernel_launch(void* const* d_in, const int* in_sizes, int n_in,
                              void* d_out, int out_size, void* d_ws, size_t ws_size,
                              hipStream_t stream)
{
    const float* hid   = (const float*)d_in[0];
    const float* noise = (const float*)d_in[1];
    const float* emb   = (const float*)d_in[2];
    const float* W     = (const float*)d_in[3];
    const float* bias  = (const float*)d_in[4];
    float* out = (float*)d_out;
    int* cnt = (int*)d_ws;
    const int B = in_sizes[0] / H;

    hipMemsetAsync(cnt, 0, GV * sizeof(int), stream);
    if (ws_size >= WS_NEED_FULL(B)) {
        _Float16* wi = (_Float16*)((char*)d_ws + WS_WI);
        _Float16* xi = (_Float16*)((char*)d_ws + WS_XI);
        float* cv = (float*)((char*)d_ws + WS_CVAL(B));
        int* ci = (int*)((char*)d_ws + WS_CIDX(B));
        prep_w<<<160, 256, 0, stream>>>(W, wi);
        prep_x<<<B / 4, 256, 0, stream>>>(hid, xi);
        gemm32i<<<(B / BM) * 5, 256, 0, stream>>>(noise, bias, wi, xi, cv, ci);
        reduce_gather<<<(B * 2) / 4, 256, 0, stream>>>(cv, ci, emb, out, cnt);
    } else if (ws_size >= (size_t)WS_NEED_MID) {
        _Float16* wi = (_Float16*)((char*)d_ws + WS_WI);
        prep_w<<<160, 256, 0, stream>>>(W, wi);
        gemm_argmax_mid<<<B / BM, 640, 0, stream>>>(hid, noise, emb, bias, wi, out, cnt);
    } else {
        fused_gemm_argmax<<<B / BM, 512, 0, stream>>>(hid, noise, emb, W, bias, out, cnt);
    }
    ppl_kernel<<<1, 64, 0, stream>>>(cnt, out + (size_t)B * 512);
}

// Round 11
// 344.587 us; speedup vs baseline: 1.2801x; 1.2801x over previous
//
#include <hip/hip_runtime.h>
#include <math.h>

#define H 512
#define GV 640
#define E_DIM 256
#define NKT 16

typedef _Float16 half8 __attribute__((ext_vector_type(8)));
typedef float f32x4 __attribute__((ext_vector_type(4)));

// ---- ws layout ----
// W image: 5 cb x 16 kt x {hi,lo} x 128 col x 4 g granules(16B) = 1.25 MB
// X image: 512 rs x 16 kt x {hi,lo} x 128 row x 4 g granules     = 128 MB
#define WS_WI   4096
#define WS_XI   (WS_WI + 2*1024*1024)
#define WS_CVAL(B) (WS_XI + (size_t)(B) * 2048)
#define WS_CIDX(B) (WS_CVAL(B) + (size_t)(B) * 40)
#define WS_NEED_FULL(B) (WS_CIDX(B) + (size_t)(B) * 40)

__device__ __forceinline__ f32x4 MF(half8 a, half8 b, f32x4 c) {
    return __builtin_amdgcn_mfma_f32_16x16x32_f16(a, b, c, 0, 0, 0);
}

// ---------------- prep W: kt-blocked hi/lo planes ----------------
// granule index within cb: kt*1024 + h*512 + col_loc*4 + g ; holds W[col][kt*32+g*8..+8]
// hi scaled by 1024, lo = unscaled residual (same 2^16 product scale -> one accumulator).
__global__ void prep_w(const float* __restrict__ W, half8* __restrict__ wv)
{
    int t = blockIdx.x * 256 + threadIdx.x;      // 0..40959
    int col = t >> 6, c = t & 63;
    int kt = c >> 2, g = c & 3;
    int cb = col >> 7, cl = col & 127;
    const float* src = W + (size_t)col * H + kt * 32 + g * 8;
    float4 v0 = *(const float4*)src;
    float4 v1 = *(const float4*)(src + 4);
    float vv[8] = {v0.x, v0.y, v0.z, v0.w, v1.x, v1.y, v1.z, v1.w};
    half8 hv, lv;
    #pragma unroll
    for (int i = 0; i < 8; ++i) {
        float ws_ = vv[i] * 1024.0f;
        _Float16 h = (_Float16)ws_;
        hv[i] = h;
        lv[i] = (_Float16)(ws_ - (float)h);
    }
    size_t base = (size_t)cb * 16384 + kt * 1024 + cl * 4 + g;
    wv[base]       = hv;
    wv[base + 512] = lv;
}

// ---------------- prep X: kt-blocked hi/lo planes per 128-row slice ----------------
// granule index within rs: kt*1024 + h*512 + row_loc*4 + g ; x scaled by 64.
__global__ void prep_x(const float* __restrict__ hid, half8* __restrict__ xv)
{
    int t = blockIdx.x * 256 + threadIdx.x;      // 0..B*64-1
    int r = t >> 6, c = t & 63;
    int kt = c >> 2, g = c & 3;
    int rs = r >> 7, row = r & 127;
    const float* src = hid + (size_t)r * H + kt * 32 + g * 8;
    float4 v0 = *(const float4*)src;
    float4 v1 = *(const float4*)(src + 4);
    float vv[8] = {v0.x, v0.y, v0.z, v0.w, v1.x, v1.y, v1.z, v1.w};
    half8 hv, lv;
    #pragma unroll
    for (int i = 0; i < 8; ++i) {
        float xs = vv[i] * 64.0f;
        _Float16 h = (_Float16)xs;
        hv[i] = h;
        lv[i] = (_Float16)(xs - (float)h);
    }
    size_t base = (size_t)rs * 16384 + kt * 1024 + row * 4 + g;
    xv[base]       = hv;
    xv[base + 512] = lv;
}

// ---------------- main GEMM: m97-structure, 128x128 tile, LDS-staged, 2 barriers/kt ---------
// Grid 2560 (XCD-chunked): lb -> rs = lb/5, cb = lb%5. 256 thr = 4 waves (wr,wc in 2x2),
// wave = 64x64 (acc[4][4]). Per kt: stage 32 KB (A,B hi/lo) via contiguous 16B/lane loads +
// XOR-slot ds_write (R2-R6-proven 0-conflict layout), then frag ds_reads + 48 MFMA/wave.
// Each wave owns (64 rows x 64-col slot) -> writes its candidates directly, no cross-wave reduce.
__global__ __launch_bounds__(256) void gemm128(
    const float* __restrict__ noise,   // (B,640)
    const float* __restrict__ bias,    // (640)
    const half8* __restrict__ wv,      // W image
    const half8* __restrict__ xv,      // X image
    float* __restrict__ cval,          // (B,10)
    int* __restrict__ cidx)            // (B,10)
{
    __shared__ __align__(16) _Float16 XH[128][32];   // 8 KB each
    __shared__ __align__(16) _Float16 XL[128][32];
    __shared__ __align__(16) _Float16 WH[128][32];
    __shared__ __align__(16) _Float16 WL[128][32];

    const int bid = blockIdx.x;
    const int lb = (bid & 7) * 320 + (bid >> 3);     // 2560 = 8*320, bijective
    const int rs = lb / 5, cb = lb - rs * 5;
    const int brow = rs * 128;

    const int tid = threadIdx.x;
    const int w = tid >> 6, wr = w >> 1, wc = w & 1;
    const int l = tid & 63, q = l & 15, g4 = l >> 4;
    const int sa = (g4 ^ ((q >> 1) & 3)) * 8;        // frag read slot (rows/cols: (x>>1)&3 == (q>>1)&3)

    f32x4 acc[4][4];
    #pragma unroll
    for (int mt = 0; mt < 4; ++mt)
        #pragma unroll
        for (int nt = 0; nt < 4; ++nt)
            acc[mt][nt] = (f32x4){0.f, 0.f, 0.f, 0.f};

    const half8* xb = xv + (size_t)rs * 16384;
    const half8* wb = wv + (size_t)cb * 16384;

    // staging identities (2 granules per plane per thread)
    const int ga0 = tid,        r0 = ga0 >> 2, s0 = ((ga0 & 3) ^ ((r0 >> 1) & 3)) * 8;
    const int ga1 = tid + 256,  r1 = ga1 >> 2, s1 = ((ga1 & 3) ^ ((r1 >> 1) & 3)) * 8;

    for (int kt = 0; kt < NKT; ++kt) {
        __syncthreads();                              // prior kt's frag reads done
        {
            const int src0 = kt * 1024 + ga0;
            const int src1 = kt * 1024 + ga1;
            *(half8*)&XH[r0][s0] = xb[src0];
            *(half8*)&XL[r0][s0] = xb[src0 + 512];
            *(half8*)&WH[r0][s0] = wb[src0];
            *(half8*)&WL[r0][s0] = wb[src0 + 512];
            *(half8*)&XH[r1][s1] = xb[src1];
            *(half8*)&XL[r1][s1] = xb[src1 + 512];
            *(half8*)&WH[r1][s1] = wb[src1];
            *(half8*)&WL[r1][s1] = wb[src1 + 512];
        }
        __syncthreads();                              // tile ready

        half8 Ah[4], Al[4];
        #pragma unroll
        for (int mt = 0; mt < 4; ++mt) {
            int ar = wr * 64 + mt * 16 + q;
            Ah[mt] = *(const half8*)&XH[ar][sa];
            Al[mt] = *(const half8*)&XL[ar][sa];
        }
        #pragma unroll
        for (int nt = 0; nt < 4; ++nt) {
            int bc = wc * 64 + nt * 16 + q;
            half8 Bh = *(const half8*)&WH[bc][sa];
            half8 Bl = *(const half8*)&WL[bc][sa];
            #pragma unroll
            for (int mt = 0; mt < 4; ++mt) {
                acc[mt][nt] = MF(Ah[mt], Bh, acc[mt][nt]);
                acc[mt][nt] = MF(Ah[mt], Bl, acc[mt][nt]);
                acc[mt][nt] = MF(Al[mt], Bh, acc[mt][nt]);
            }
        }
    }

    // ---- epilogue: z = logits + bias + gumbel; per-row argmax over wave's 64 cols ----
    const float C1 = 1.52587890625e-05f;             // 2^-16 (64*1024 product scale)
    float bcol[4];
    #pragma unroll
    for (int nt = 0; nt < 4; ++nt) bcol[nt] = bias[cb * 128 + wc * 64 + nt * 16 + q];

    const int cb10 = cb * 2 + wc;                    // candidate slot 0..9
    #pragma unroll
    for (int mt = 0; mt < 4; ++mt) {
        #pragma unroll
        for (int reg = 0; reg < 4; ++reg) {
            const int rloc = wr * 64 + mt * 16 + g4 * 4 + reg;
            float bv = -INFINITY;
            int bn = 0;
            #pragma unroll
            for (int nt = 0; nt < 4; ++nt) {
                int col = cb * 128 + wc * 64 + nt * 16 + q;
                float u = noise[(size_t)(brow + rloc) * GV + col];
                float gum = -logf(-logf(u + 1e-10f) + 1e-10f);
                float z = acc[mt][nt][reg] * C1 + bcol[nt] + gum;
                if (z > bv) { bv = z; bn = col; }            // ascending: first-wins
            }
            #pragma unroll
            for (int m = 1; m < 16; m <<= 1) {               // 16-lane argmax reduce
                float ov = __shfl_xor(bv, m, 64);
                int on = __shfl_xor(bn, m, 64);
                if (ov > bv || (ov == bv && on < bn)) { bv = ov; bn = on; }
            }
            if (q == 0) {
                cval[(size_t)(brow + rloc) * 10 + cb10] = bv;
                cidx[(size_t)(brow + rloc) * 10 + cb10] = bn;
            }
        }
    }
}

// ---------------- reduce: final argmax per (row,group), histogram, gather ----------------
__global__ __launch_bounds__(256) void reduce_gather(
    const float* __restrict__ cval, const int* __restrict__ cidx,
    const float* __restrict__ emb, float* __restrict__ out, int* __restrict__ cnt)
{
    const int tid = threadIdx.x;
    const int task = blockIdx.x * 4 + (tid >> 6);
    const int lane = tid & 63;
    const int row = task >> 1, grp = task & 1;

    float bv = -INFINITY;
    int bn = 0;
    #pragma unroll
    for (int cbs = 0; cbs < 5; ++cbs) {
        float v = cval[(size_t)row * 10 + grp * 5 + cbs];
        int n = cidx[(size_t)row * 10 + grp * 5 + cbs];
        if (v > bv) { bv = v; bn = n; }                      // ascending colblk
    }
    if (lane == 0) atomicAdd(&cnt[bn], 1);
    const float4* src = (const float4*)(emb + (size_t)bn * E_DIM);
    float4* dst = (float4*)(out + (size_t)row * 512 + grp * 256);
    dst[lane] = src[lane];
}

__global__ void ppl_kernel(const int* __restrict__ cnt, float* __restrict__ outp)
{
    const int lane = threadIdx.x;
    float total = 0.f;
    #pragma unroll
    for (int gg = 0; gg < 2; ++gg) {
        float s = 0.f;
        for (int v = lane; v < 320; v += 64) {
            float m = (float)cnt[gg * 320 + v] * (1.0f / 65536.0f);
            s += m * logf(m + 1e-7f);
        }
        #pragma unroll
        for (int msk = 1; msk <= 32; msk <<= 1) s += __shfl_xor(s, msk, 64);
        total += expf(-s);
    }
    if (lane == 0) *outp = total;
}

// ---------------- last-resort fp32 fallback (round-1, passed at 724 us) ----------------
__global__ __launch_bounds__(512) void fused_gemm_argmax(
    const float* __restrict__ hid, const float* __restrict__ noise,
    const float* __restrict__ emb, const float* __restrict__ W,
    const float* __restrict__ bias, float* __restrict__ out, int* __restrict__ cnt)
{
    __shared__ float A_lds[16][64];
    __shared__ float B_lds[16][GV + 4];
    const int tid = threadIdx.x;
    const int tx = tid & 63, ty = tid >> 6;
    const int brow = blockIdx.x * 64;
    const int nbase = tx * 10;
    float acc[8][10];
    #pragma unroll
    for (int i = 0; i < 8; ++i)
        #pragma unroll
        for (int j = 0; j < 10; ++j) acc[i][j] = 0.f;
    for (int t = 0; t < H; t += 16) {
        if (t) __syncthreads();
        if (tid < 256) {
            int m = tid & 63, kq = tid >> 6;
            float4 v = *(const float4*)(hid + (size_t)(brow + m) * H + t + kq * 4);
            A_lds[kq * 4 + 0][m] = v.x; A_lds[kq * 4 + 1][m] = v.y;
            A_lds[kq * 4 + 2][m] = v.z; A_lds[kq * 4 + 3][m] = v.w;
        }
        #pragma unroll
        for (int s = 0; s < 5; ++s) {
            int c = tid + s * 512;
            int n = c % 640, kq = c / 640;
            float4 v = *(const float4*)(W + (size_t)n * H + t + kq * 4);
            B_lds[kq * 4 + 0][n] = v.x; B_lds[kq * 4 + 1][n] = v.y;
            B_lds[kq * 4 + 2][n] = v.z; B_lds[kq * 4 + 3][n] = v.w;
        }
        __syncthreads();
        #pragma unroll 4
        for (int kk = 0; kk < 16; ++kk) {
            float a[8], bb[10];
            #pragma unroll
            for (int i = 0; i < 8; ++i) a[i] = A_lds[kk][ty * 8 + i];
            #pragma unroll
            for (int j = 0; j < 10; ++j) bb[j] = B_lds[kk][nbase + j];
            #pragma unroll
            for (int i = 0; i < 8; ++i)
                #pragma unroll
                for (int j = 0; j < 10; ++j) acc[i][j] = fmaf(a[i], bb[j], acc[i][j]);
        }
    }
    float bs[10];
    #pragma unroll
    for (int j = 0; j < 10; ++j) bs[j] = bias[nbase + j];
    const int gg = tx >> 5, ll = tx & 31;
    #pragma unroll
    for (int i = 0; i < 8; ++i) {
        const int b = brow + ty * 8 + i;
        float best = -INFINITY; int bestn = nbase;
        #pragma unroll
        for (int j = 0; j < 10; ++j) {
            float u = noise[(size_t)b * GV + nbase + j];
            float gmb = -logf(-logf(u + 1e-10f) + 1e-10f);
            float z = acc[i][j] + bs[j] + gmb;
            if (z > best) { best = z; bestn = nbase + j; }
        }
        #pragma unroll
        for (int msk = 1; msk <= 16; msk <<= 1) {
            float oz = __shfl_xor(best, msk, 64);
            int on = __shfl_xor(bestn, msk, 64);
            if (oz > best || (oz == best && on < bestn)) { best = oz; bestn = on; }
        }
        if (ll == 0) atomicAdd(&cnt[bestn], 1);
        const float4* src = (const float4*)(emb + (size_t)bestn * E_DIM);
        float4* dst = (float4*)(out + (size_t)b * 512 + gg * 256);
        dst[ll] = src[ll];
        dst[ll + 32] = src[ll + 32];
    }
}

extern "C" void kernel_launch(void* const* d_in, const int* in_sizes, int n_in,
                              void* d_out, int out_size, void* d_ws, size_t ws_size,
                              hipStream_t stream)
{
    const float* hid   = (const float*)d_in[0];
    const float* noise = (const float*)d_in[1];
    const float* emb   = (const float*)d_in[2];
    const float* W     = (const float*)d_in[3];
    const float* bias  = (const float*)d_in[4];
    float* out = (float*)d_out;
    int* cnt = (int*)d_ws;
    const int B = in_sizes[0] / H;   // 65536

    hipMemsetAsync(cnt, 0, GV * sizeof(int), stream);
    if (ws_size >= WS_NEED_FULL(B) && (B % 128) == 0) {
        half8* wv = (half8*)((char*)d_ws + WS_WI);
        half8* xv = (half8*)((char*)d_ws + WS_XI);
        float* cv = (float*)((char*)d_ws + WS_CVAL(B));
        int*   ci = (int*)((char*)d_ws + WS_CIDX(B));
        prep_w<<<160, 256, 0, stream>>>(W, wv);
        prep_x<<<B / 4, 256, 0, stream>>>(hid, xv);
        gemm128<<<(B / 128) * 5, 256, 0, stream>>>(noise, bias, wv, xv, cv, ci);
        reduce_gather<<<(B * 2) / 4, 256, 0, stream>>>(cv, ci, emb, out, cnt);
    } else {
        fused_gemm_argmax<<<B / 64, 512, 0, stream>>>(hid, noise, emb, W, bias, out, cnt);
    }
    ppl_kernel<<<1, 64, 0, stream>>>(cnt, out + (size_t)B * 512);
}

// Round 12
// 343.880 us; speedup vs baseline: 1.2827x; 1.0021x over previous
//
#include <hip/hip_runtime.h>
#include <math.h>

#define H 512
#define GV 640
#define E_DIM 256
#define NKT 16

typedef _Float16 half8 __attribute__((ext_vector_type(8)));
typedef float f32x4 __attribute__((ext_vector_type(4)));

// ---- ws layout ----
// W image: 5 cb x 16 kt x {hi 512, lo 512} granules(16B), pre-swizzled  = 1.25 MB
// X image: (B/128) rs x 16 kt x {hi 512, lo 512} granules, pre-swizzled = 128 MB @ B=64k
#define WS_WI   4096
#define WS_XI   (WS_WI + 2*1024*1024)
#define WS_CVAL(B) (WS_XI + (size_t)(B) * 2048)
#define WS_CIDX(B) (WS_CVAL(B) + (size_t)(B) * 40)
#define WS_NEED_FULL(B) (WS_CIDX(B) + (size_t)(B) * 40)

__device__ __forceinline__ f32x4 MF(half8 a, half8 b, f32x4 c) {
    return __builtin_amdgcn_mfma_f32_16x16x32_f16(a, b, c, 0, 0, 0);
}

// HBM/L2 -> LDS direct, 16 B per lane. LDS dest = uniform base + lane*16 (linear);
// swizzle is baked into the image order (rule: linear dest + inverse-swz source + swz read).
#define GLD16(GP, LP) __builtin_amdgcn_global_load_lds( \
    (const __attribute__((address_space(1))) void*)(GP), \
    (__attribute__((address_space(3))) void*)(LP), 16, 0, 0)

// ---------------- prep W: f32 -> fp16 hi/lo image, kt-blocked, PRE-SWIZZLED ----------------
// Source chunk (col, kc) lands at granule  kt*1024 + cl*4 + (kc ^ ((cl>>1)&3))  (+512 for lo).
// hi scaled by 1024, lo = unscaled residual (same 2^16 product scale -> one accumulator).
__global__ void prep_w(const float* __restrict__ W, half8* __restrict__ wv)
{
    int t = blockIdx.x * 256 + threadIdx.x;      // 0..40959
    int col = t >> 6, c = t & 63;
    int kt = c >> 2, g = c & 3;
    int cb = col >> 7, cl = col & 127;
    const float* src = W + (size_t)col * H + kt * 32 + g * 8;
    float4 v0 = *(const float4*)src;
    float4 v1 = *(const float4*)(src + 4);
    float vv[8] = {v0.x, v0.y, v0.z, v0.w, v1.x, v1.y, v1.z, v1.w};
    half8 hv, lv;
    #pragma unroll
    for (int i = 0; i < 8; ++i) {
        float ws_ = vv[i] * 1024.0f;
        _Float16 h = (_Float16)ws_;
        hv[i] = h;
        lv[i] = (_Float16)(ws_ - (float)h);
    }
    int gsw = g ^ ((cl >> 1) & 3);
    size_t base = (size_t)cb * 16384 + kt * 1024 + cl * 4 + gsw;
    wv[base]       = hv;
    wv[base + 512] = lv;
}

// ---------------- prep X: same layout per 128-row slice, x scaled by 64 ----------------
__global__ void prep_x(const float* __restrict__ hid, half8* __restrict__ xv)
{
    int t = blockIdx.x * 256 + threadIdx.x;      // 0..B*64-1
    int r = t >> 6, c = t & 63;
    int kt = c >> 2, g = c & 3;
    int rs = r >> 7, row = r & 127;
    const float* src = hid + (size_t)r * H + kt * 32 + g * 8;
    float4 v0 = *(const float4*)src;
    float4 v1 = *(const float4*)(src + 4);
    float vv[8] = {v0.x, v0.y, v0.z, v0.w, v1.x, v1.y, v1.z, v1.w};
    half8 hv, lv;
    #pragma unroll
    for (int i = 0; i < 8; ++i) {
        float xs = vv[i] * 64.0f;
        _Float16 h = (_Float16)xs;
        hv[i] = h;
        lv[i] = (_Float16)(xs - (float)h);
    }
    int gsw = g ^ ((row >> 1) & 3);
    size_t base = (size_t)rs * 16384 + kt * 1024 + row * 4 + gsw;
    xv[base]       = hv;
    xv[base + 512] = lv;
}

// ---------------- main GEMM: 128x128 tile, global_load_lds staging, 2 barriers/kt ---------
// Grid 2560 (XCD-chunked): lb -> rs = lb/5, cb = lb%5. 256 thr = 4 waves (wr,wc in 2x2),
// wave = 64x64 (acc[4][4] = 64 AGPR). Staging: 8 x global_load_lds(16B)/thread/kt -- no
// staging VGPRs, no ds_writes; LDS image arrives pre-swizzled -> frag reads conflict-free
// (layout byte-identical to R11's measured-0-conflict scheme).
__global__ __launch_bounds__(256) void gemm128(
    const float* __restrict__ noise,   // (B,640)
    const float* __restrict__ bias,    // (640)
    const half8* __restrict__ wv,      // W image (pre-swizzled)
    const half8* __restrict__ xv,      // X image (pre-swizzled)
    float* __restrict__ cval,          // (B,10)
    int* __restrict__ cidx)            // (B,10)
{
    __shared__ __align__(16) _Float16 XH[128][32];   // 8 KB each, 32 KB total
    __shared__ __align__(16) _Float16 XL[128][32];
    __shared__ __align__(16) _Float16 WH[128][32];
    __shared__ __align__(16) _Float16 WL[128][32];

    const int bid = blockIdx.x;
    const int lb = (bid & 7) * 320 + (bid >> 3);     // 2560 = 8*320, bijective
    const int rs = lb / 5, cb = lb - rs * 5;
    const int brow = rs * 128;

    const int tid = threadIdx.x;
    const int w = tid >> 6, wr = w >> 1, wc = w & 1;
    const int l = tid & 63, q = l & 15, g4 = l >> 4;
    const int sa = (g4 ^ ((q >> 1) & 3)) * 8;        // swizzled frag-read slot (halves)

    f32x4 acc[4][4];
    #pragma unroll
    for (int mt = 0; mt < 4; ++mt)
        #pragma unroll
        for (int nt = 0; nt < 4; ++nt)
            acc[mt][nt] = (f32x4){0.f, 0.f, 0.f, 0.f};

    const half8* xb = xv + (size_t)rs * 16384;
    const half8* wb = wv + (size_t)cb * 16384;

    // LDS staging bases: wave-uniform, lane writes base + lane*16.
    const int wb64 = w * 64;                         // wave-uniform
    char* ldsXH = (char*)&XH[0][0];
    char* ldsXL = (char*)&XL[0][0];
    char* ldsWH = (char*)&WH[0][0];
    char* ldsWL = (char*)&WL[0][0];

    for (int kt = 0; kt < NKT; ++kt) {
        __syncthreads();                              // prior kt's frag reads done
        {
            const int s0 = kt * 1024 + tid;           // granule: j=0 (tid), j=1 (tid+256)
            const int s1 = s0 + 256;
            const int d0 = (wb64) * 16;               // lds byte base, j=0
            const int d1 = (wb64 + 256) * 16;         // j=1
            GLD16(&xb[s0],       ldsXH + d0);
            GLD16(&xb[s1],       ldsXH + d1);
            GLD16(&xb[s0 + 512], ldsXL + d0);
            GLD16(&xb[s1 + 512], ldsXL + d1);
            GLD16(&wb[s0],       ldsWH + d0);
            GLD16(&wb[s1],       ldsWH + d1);
            GLD16(&wb[s0 + 512], ldsWL + d0);
            GLD16(&wb[s1 + 512], ldsWL + d1);
        }
        __syncthreads();                              // vmcnt(0) drained by compiler

        half8 Ah[4], Al[4];
        #pragma unroll
        for (int mt = 0; mt < 4; ++mt) {
            int ar = wr * 64 + mt * 16 + q;
            Ah[mt] = *(const half8*)&XH[ar][sa];
            Al[mt] = *(const half8*)&XL[ar][sa];
        }
        #pragma unroll
        for (int nt = 0; nt < 4; ++nt) {
            int bc = wc * 64 + nt * 16 + q;
            half8 Bh = *(const half8*)&WH[bc][sa];
            half8 Bl = *(const half8*)&WL[bc][sa];
            #pragma unroll
            for (int mt = 0; mt < 4; ++mt) {
                acc[mt][nt] = MF(Ah[mt], Bh, acc[mt][nt]);
                acc[mt][nt] = MF(Ah[mt], Bl, acc[mt][nt]);
                acc[mt][nt] = MF(Al[mt], Bh, acc[mt][nt]);
            }
        }
    }

    // ---- epilogue: z = logits + bias + gumbel; per-row argmax over wave's 64 cols ----
    const float C1 = 1.52587890625e-05f;             // 2^-16 (64*1024 product scale)
    float bcol[4];
    #pragma unroll
    for (int nt = 0; nt < 4; ++nt) bcol[nt] = bias[cb * 128 + wc * 64 + nt * 16 + q];

    const int cb10 = cb * 2 + wc;                    // candidate slot 0..9
    #pragma unroll
    for (int mt = 0; mt < 4; ++mt) {
        #pragma unroll
        for (int reg = 0; reg < 4; ++reg) {
            const int rloc = wr * 64 + mt * 16 + g4 * 4 + reg;
            float bv = -INFINITY;
            int bn = 0;
            #pragma unroll
            for (int nt = 0; nt < 4; ++nt) {
                int col = cb * 128 + wc * 64 + nt * 16 + q;
                float u = noise[(size_t)(brow + rloc) * GV + col];
                float gum = -__logf(-__logf(u + 1e-10f) + 1e-10f);
                float z = acc[mt][nt][reg] * C1 + bcol[nt] + gum;
                if (z > bv) { bv = z; bn = col; }            // ascending: first-wins
            }
            #pragma unroll
            for (int m = 1; m < 16; m <<= 1) {               // 16-lane argmax reduce
                float ov = __shfl_xor(bv, m, 64);
                int on = __shfl_xor(bn, m, 64);
                if (ov > bv || (ov == bv && on < bn)) { bv = ov; bn = on; }
            }
            if (q == 0) {
                cval[(size_t)(brow + rloc) * 10 + cb10] = bv;
                cidx[(size_t)(brow + rloc) * 10 + cb10] = bn;
            }
        }
    }
}

// ---------------- reduce: final argmax per (row,group), histogram, gather ----------------
__global__ __launch_bounds__(256) void reduce_gather(
    const float* __restrict__ cval, const int* __restrict__ cidx,
    const float* __restrict__ emb, float* __restrict__ out, int* __restrict__ cnt)
{
    const int tid = threadIdx.x;
    const int task = blockIdx.x * 4 + (tid >> 6);
    const int lane = tid & 63;
    const int row = task >> 1, grp = task & 1;

    float bv = -INFINITY;
    int bn = 0;
    #pragma unroll
    for (int cbs = 0; cbs < 5; ++cbs) {
        float v = cval[(size_t)row * 10 + grp * 5 + cbs];
        int n = cidx[(size_t)row * 10 + grp * 5 + cbs];
        if (v > bv) { bv = v; bn = n; }                      // ascending colblk
    }
    if (lane == 0) atomicAdd(&cnt[bn], 1);
    const float4* src = (const float4*)(emb + (size_t)bn * E_DIM);
    float4* dst = (float4*)(out + (size_t)row * 512 + grp * 256);
    dst[lane] = src[lane];
}

__global__ void ppl_kernel(const int* __restrict__ cnt, float* __restrict__ outp)
{
    const int lane = threadIdx.x;
    float total = 0.f;
    #pragma unroll
    for (int gg = 0; gg < 2; ++gg) {
        float s = 0.f;
        for (int v = lane; v < 320; v += 64) {
            float m = (float)cnt[gg * 320 + v] * (1.0f / 65536.0f);
            s += m * logf(m + 1e-7f);
        }
        #pragma unroll
        for (int msk = 1; msk <= 32; msk <<= 1) s += __shfl_xor(s, msk, 64);
        total += expf(-s);
    }
    if (lane == 0) *outp = total;
}

// ---------------- last-resort fp32 fallback (round-1, passed at 724 us) ----------------
__global__ __launch_bounds__(512) void fused_gemm_argmax(
    const float* __restrict__ hid, const float* __restrict__ noise,
    const float* __restrict__ emb, const float* __restrict__ W,
    const float* __restrict__ bias, float* __restrict__ out, int* __restrict__ cnt)
{
    __shared__ float A_lds[16][64];
    __shared__ float B_lds[16][GV + 4];
    const int tid = threadIdx.x;
    const int tx = tid & 63, ty = tid >> 6;
    const int brow = blockIdx.x * 64;
    const int nbase = tx * 10;
    float acc[8][10];
    #pragma unroll
    for (int i = 0; i < 8; ++i)
        #pragma unroll
        for (int j = 0; j < 10; ++j) acc[i][j] = 0.f;
    for (int t = 0; t < H; t += 16) {
        if (t) __syncthreads();
        if (tid < 256) {
            int m = tid & 63, kq = tid >> 6;
            float4 v = *(const float4*)(hid + (size_t)(brow + m) * H + t + kq * 4);
            A_lds[kq * 4 + 0][m] = v.x; A_lds[kq * 4 + 1][m] = v.y;
            A_lds[kq * 4 + 2][m] = v.z; A_lds[kq * 4 + 3][m] = v.w;
        }
        #pragma unroll
        for (int s = 0; s < 5; ++s) {
            int c = tid + s * 512;
            int n = c % 640, kq = c / 640;
            float4 v = *(const float4*)(W + (size_t)n * H + t + kq * 4);
            B_lds[kq * 4 + 0][n] = v.x; B_lds[kq * 4 + 1][n] = v.y;
            B_lds[kq * 4 + 2][n] = v.z; B_lds[kq * 4 + 3][n] = v.w;
        }
        __syncthreads();
        #pragma unroll 4
        for (int kk = 0; kk < 16; ++kk) {
            float a[8], bb[10];
            #pragma unroll
            for (int i = 0; i < 8; ++i) a[i] = A_lds[kk][ty * 8 + i];
            #pragma unroll
            for (int j = 0; j < 10; ++j) bb[j] = B_lds[kk][nbase + j];
            #pragma unroll
            for (int i = 0; i < 8; ++i)
                #pragma unroll
                for (int j = 0; j < 10; ++j) acc[i][j] = fmaf(a[i], bb[j], acc[i][j]);
        }
    }
    float bs[10];
    #pragma unroll
    for (int j = 0; j < 10; ++j) bs[j] = bias[nbase + j];
    const int gg = tx >> 5, ll = tx & 31;
    #pragma unroll
    for (int i = 0; i < 8; ++i) {
        const int b = brow + ty * 8 + i;
        float best = -INFINITY; int bestn = nbase;
        #pragma unroll
        for (int j = 0; j < 10; ++j) {
            float u = noise[(size_t)b * GV + nbase + j];
            float gmb = -logf(-logf(u + 1e-10f) + 1e-10f);
            float z = acc[i][j] + bs[j] + gmb;
            if (z > best) { best = z; bestn = nbase + j; }
        }
        #pragma unroll
        for (int msk = 1; msk <= 16; msk <<= 1) {
            float oz = __shfl_xor(best, msk, 64);
            int on = __shfl_xor(bestn, msk, 64);
            if (oz > best || (oz == best && on < bestn)) { best = oz; bestn = on; }
        }
        if (ll == 0) atomicAdd(&cnt[bestn], 1);
        const float4* src = (const float4*)(emb + (size_t)bestn * E_DIM);
        float4* dst = (float4*)(out + (size_t)b * 512 + gg * 256);
        dst[ll] = src[ll];
        dst[ll + 32] = src[ll + 32];
    }
}

extern "C" void kernel_launch(void* const* d_in, const int* in_sizes, int n_in,
                              void* d_out, int out_size, void* d_ws, size_t ws_size,
                              hipStream_t stream)
{
    const float* hid   = (const float*)d_in[0];
    const float* noise = (const float*)d_in[1];
    const float* emb   = (const float*)d_in[2];
    const float* W     = (const float*)d_in[3];
    const float* bias  = (const float*)d_in[4];
    float* out = (float*)d_out;
    int* cnt = (int*)d_ws;
    const int B = in_sizes[0] / H;   // 65536

    hipMemsetAsync(cnt, 0, GV * sizeof(int), stream);
    if (ws_size >= WS_NEED_FULL(B) && (B % 128) == 0) {
        half8* wv = (half8*)((char*)d_ws + WS_WI);
        half8* xv = (half8*)((char*)d_ws + WS_XI);
        float* cv = (float*)((char*)d_ws + WS_CVAL(B));
        int*   ci = (int*)((char*)d_ws + WS_CIDX(B));
        prep_w<<<160, 256, 0, stream>>>(W, wv);
        prep_x<<<B / 4, 256, 0, stream>>>(hid, xv);
        gemm128<<<(B / 128) * 5, 256, 0, stream>>>(noise, bias, wv, xv, cv, ci);
        reduce_gather<<<(B * 2) / 4, 256, 0, stream>>>(cv, ci, emb, out, cnt);
    } else {
        fused_gemm_argmax<<<B / 64, 512, 0, stream>>>(hid, noise, emb, W, bias, out, cnt);
    }
    ppl_kernel<<<1, 64, 0, stream>>>(cnt, out + (size_t)B * 512);
}